// Round 1
// baseline (32224.182 us; speedup 1.0000x reference)
//
#include <hip/hip_runtime.h>

typedef _Float16 half_t;
typedef _Float16 half8 __attribute__((ext_vector_type(8)));
typedef _Float16 half4_t __attribute__((ext_vector_type(4)));
typedef float v4f __attribute__((ext_vector_type(4)));

#define SEQ 1024
#define NBATCH 64
#define HDIM 512
#define NBLK 32              // 512 h-dims / 16 per block
#define HSEQ_ELEMS ((size_t)SEQ * NBATCH * HDIM)

// ---------------- fp32 -> fp16 conversion (vectorized) ----------------
__global__ void conv_f2h(const float4* __restrict__ src, half4_t* __restrict__ dst, int n4) {
    int idx = blockIdx.x * blockDim.x + threadIdx.x;
    int stride = gridDim.x * blockDim.x;
    for (int i = idx; i < n4; i += stride) {
        float4 v = src[i];
        half4_t h;
        h[0] = (half_t)v.x; h[1] = (half_t)v.y; h[2] = (half_t)v.z; h[3] = (half_t)v.w;
        dst[i] = h;
    }
}

// ---------------- init h buffer + step counters ----------------
__global__ void prep_kernel(const float* __restrict__ h0, half_t* __restrict__ hbuf,
                            unsigned int* __restrict__ ctr) {
    int idx = blockIdx.x * 256 + threadIdx.x;
    if (idx < NBATCH * HDIM) hbuf[idx] = (half_t)h0[idx];
    if (idx < SEQ) ctr[idx] = 0;
}

// ---------------- persistent recurrent kernel ----------------
// 32 blocks x 256 threads. Block owns h-dims [j0, j0+16). Wave w = gate type
// (0=f,1=i,2=g,3=o): computes its 16 gate rows for all 64 batches via MFMA
// with weights held in registers. Gates exchanged via LDS; c in registers.
__global__ __launch_bounds__(256, 1) void lstm_rec(
    const half_t* __restrict__ xh,   // (SEQ*64, 512) fp16
    const half_t* __restrict__ wi,   // (2048, 512) fp16
    const half_t* __restrict__ wh,   // (2048, 512) fp16
    const float*  __restrict__ bi,   // (2048)
    const float*  __restrict__ bh,   // (2048)
    const float*  __restrict__ c0,   // (64, 512)
    float*        __restrict__ out,  // h_seq | h | c
    half_t*       __restrict__ hbuf, // 2 * 64*512 fp16
    unsigned int* ctr)               // SEQ counters
{
    const int tid    = threadIdx.x;
    const int lane   = tid & 63;
    const int w      = tid >> 6;       // gate type 0..3
    const int lane16 = lane & 15;
    const int lgrp   = lane >> 4;      // 0..3
    const int k8     = lgrp * 8;
    const int j0     = blockIdx.x * 16;
    const int g      = w * 512 + j0 + lane16;   // global gate row

    // ---- preload weight fragments (resident whole kernel) ----
    half8 bfi[16], bfh[16];
#pragma unroll
    for (int kt = 0; kt < 16; ++kt) {
        bfi[kt] = *(const half8*)&wi[(size_t)g * 512 + kt * 32 + k8];
        bfh[kt] = *(const half8*)&wh[(size_t)g * 512 + kt * 32 + k8];
    }
    const float bsum = bi[g] + bh[g];

    // ---- c state in registers: lane handles (m = mE+r, j = j0+lane16) ----
    const int mE = w * 16 + lgrp * 4;
    float c[4];
#pragma unroll
    for (int r = 0; r < 4; ++r)
        c[r] = c0[(mE + r) * HDIM + j0 + lane16];

    __shared__ float glds[4 * 64 * 16];   // [gate][m][j-col] fp32, 16 KB

    for (int t = 0; t < SEQ; ++t) {
        const half_t* hin  = hbuf + (t & 1) * (NBATCH * HDIM);
        half_t*       hout = hbuf + ((t + 1) & 1) * (NBATCH * HDIM);

        if (t > 0) {
            if (tid == 0) {
                while (__hip_atomic_load(&ctr[t - 1], __ATOMIC_RELAXED,
                                         __HIP_MEMORY_SCOPE_AGENT) < NBLK)
                    __builtin_amdgcn_s_sleep(1);
            }
            __syncthreads();
            __builtin_amdgcn_fence(__ATOMIC_ACQUIRE, "agent");
        }

        v4f acc[4];
#pragma unroll
        for (int fm = 0; fm < 4; ++fm) acc[fm] = (v4f)0.f;

        // x_t @ Wi^T  (K = 512)
        const half_t* xt = xh + (size_t)t * (NBATCH * HDIM);
#pragma unroll
        for (int kt = 0; kt < 16; ++kt) {
#pragma unroll
            for (int fm = 0; fm < 4; ++fm) {
                half8 a = *(const half8*)&xt[(fm * 16 + lane16) * HDIM + kt * 32 + k8];
                acc[fm] = __builtin_amdgcn_mfma_f32_16x16x32_f16(a, bfi[kt], acc[fm], 0, 0, 0);
            }
        }
        // h_{t-1} @ Wh^T  (K = 512)
#pragma unroll
        for (int kt = 0; kt < 16; ++kt) {
#pragma unroll
            for (int fm = 0; fm < 4; ++fm) {
                half8 a = *(const half8*)&hin[(fm * 16 + lane16) * HDIM + kt * 32 + k8];
                acc[fm] = __builtin_amdgcn_mfma_f32_16x16x32_f16(a, bfh[kt], acc[fm], 0, 0, 0);
            }
        }

        // ---- write this wave's gates (with bias) to LDS ----
        // C frag layout (m89-verified): col = lane&15, row(m) = fm*16 + 4*lgrp + r
#pragma unroll
        for (int fm = 0; fm < 4; ++fm)
#pragma unroll
            for (int r = 0; r < 4; ++r)
                glds[(w * 64 + fm * 16 + lgrp * 4 + r) * 16 + lane16] = acc[fm][r] + bsum;
        __syncthreads();

        // ---- elementwise: wave w handles batches [w*16, w*16+16) ----
        const int jcol = j0 + lane16;
#pragma unroll
        for (int r = 0; r < 4; ++r) {
            const int m = mE + r;
            float F  = glds[(0 * 64 + m) * 16 + lane16];
            float I  = glds[(1 * 64 + m) * 16 + lane16];
            float G  = glds[(2 * 64 + m) * 16 + lane16];
            float O  = glds[(3 * 64 + m) * 16 + lane16];
            float f  = 1.f / (1.f + expf(-F));
            float i  = 1.f / (1.f + expf(-I));
            float gg = tanhf(G);
            float o  = 1.f / (1.f + expf(-O));
            float cn = f * c[r] + i * gg;
            c[r] = cn;
            float h = o * tanhf(cn);
            out[((size_t)t * NBATCH + m) * HDIM + jcol] = h;
            hout[m * HDIM + jcol] = (half_t)h;
            if (t == SEQ - 1) {
                out[HSEQ_ELEMS + (size_t)m * HDIM + jcol] = h;                    // final h
                out[HSEQ_ELEMS + (size_t)NBATCH * HDIM + (size_t)m * HDIM + jcol] = cn; // final c
            }
        }
        __syncthreads();   // drains all waves' global stores (vmcnt) before publish
        if (tid == 0)
            __hip_atomic_fetch_add(&ctr[t], 1u, __ATOMIC_RELEASE, __HIP_MEMORY_SCOPE_AGENT);
    }
}

// ---------------- launch ----------------
extern "C" void kernel_launch(void* const* d_in, const int* in_sizes, int n_in,
                              void* d_out, int out_size, void* d_ws, size_t ws_size,
                              hipStream_t stream) {
    const float* x  = (const float*)d_in[0];
    const float* h0 = (const float*)d_in[1];
    const float* c0 = (const float*)d_in[2];
    const float* Wi = (const float*)d_in[3];
    const float* bi = (const float*)d_in[4];
    const float* Wh = (const float*)d_in[5];
    const float* bh = (const float*)d_in[6];
    float* out = (float*)d_out;

    char* ws = (char*)d_ws;
    // ws layout (bytes): ctr @0 (4K) | hbuf @4096 (128K) | Wi_h @135168 (2M)
    //                    | Wh_h @2232320 (2M) | x_h @4329472 (64M)  => ~71.5 MB total
    unsigned int* ctr  = (unsigned int*)(ws + 0);
    half_t*       hbuf = (half_t*)(ws + 4096);
    half_t*       wi_h = (half_t*)(ws + 135168);
    half_t*       wh_h = (half_t*)(ws + 135168 + 2097152);
    half_t*       x_h  = (half_t*)(ws + 135168 + 2 * 2097152);

    conv_f2h<<<4096, 256, 0, stream>>>((const float4*)x,  (half4_t*)x_h,  (SEQ * NBATCH * HDIM) / 4);
    conv_f2h<<<1024, 256, 0, stream>>>((const float4*)Wi, (half4_t*)wi_h, (4 * HDIM * HDIM) / 4);
    conv_f2h<<<1024, 256, 0, stream>>>((const float4*)Wh, (half4_t*)wh_h, (4 * HDIM * HDIM) / 4);
    prep_kernel<<<128, 256, 0, stream>>>(h0, hbuf, ctr);
    lstm_rec<<<NBLK, 256, 0, stream>>>(x_h, wi_h, wh_h, bi, bh, c0, out, hbuf, ctr);
}

// Round 2
// 18061.546 us; speedup vs baseline: 1.7841x; 1.7841x over previous
//
#include <hip/hip_runtime.h>

typedef _Float16 half_t;
typedef _Float16 half8 __attribute__((ext_vector_type(8)));
typedef _Float16 half4_t __attribute__((ext_vector_type(4)));
typedef float v4f __attribute__((ext_vector_type(4)));
typedef unsigned int u32x4 __attribute__((ext_vector_type(4)));

#define SEQ 1024
#define NBATCH 64
#define HDIM 512
#define NBLK 32
#define HSEQ_ELEMS ((size_t)SEQ * NBATCH * HDIM)

__device__ __forceinline__ float fsig(float x)  { return 1.f / (1.f + __expf(-x)); }
__device__ __forceinline__ float ftanh(float x) { return 1.f - 2.f / (__expf(2.f * x) + 1.f); }

// ---------------- fp32 -> fp16 conversion (vectorized) ----------------
__global__ void conv_f2h(const float4* __restrict__ src, half4_t* __restrict__ dst, int n4) {
    int idx = blockIdx.x * blockDim.x + threadIdx.x;
    int stride = gridDim.x * blockDim.x;
    for (int i = idx; i < n4; i += stride) {
        float4 v = src[i];
        half4_t h;
        h[0] = (half_t)v.x; h[1] = (half_t)v.y; h[2] = (half_t)v.z; h[3] = (half_t)v.w;
        dst[i] = h;
    }
}

// ---------------- init h buffer + per-step flags (every launch) ----------------
__global__ void prep_kernel(const float* __restrict__ h0, half_t* __restrict__ hbuf,
                            unsigned int* __restrict__ flags) {
    int idx = blockIdx.x * 256 + threadIdx.x;
    if (idx < NBATCH * HDIM) hbuf[idx] = (half_t)h0[idx];
    if (idx < SEQ * NBLK) flags[idx] = 0u;
}

// ---------------- persistent recurrent kernel ----------------
// 32 blocks x 256 threads. Block owns h-dims [j0, j0+16); wave w = gate type.
// Weights register-resident. Cross-block h exchange via sc0/sc1 device-coherent
// loads/stores (no cache invalidates). x-projection MFMAs for step t+1 run off
// the critical path after publishing h_t.
__global__ __launch_bounds__(256, 1) void lstm_rec(
    const half_t* __restrict__ xh,   // (SEQ*64, 512) fp16
    const half_t* __restrict__ wi,   // (2048, 512) fp16
    const half_t* __restrict__ wh,   // (2048, 512) fp16
    const float*  __restrict__ bi,   // (2048)
    const float*  __restrict__ bh,   // (2048)
    const float*  __restrict__ c0,   // (64, 512)
    float*        __restrict__ out,  // h_seq | h | c
    half_t*       __restrict__ hbuf, // 2 * 64*512 fp16 ring
    unsigned int* __restrict__ flags)// SEQ * NBLK
{
    const int tid    = threadIdx.x;
    const int lane   = tid & 63;
    const int w      = tid >> 6;       // gate type 0..3
    const int lane16 = lane & 15;
    const int lgrp   = lane >> 4;      // 0..3
    const int k8     = lgrp * 8;
    const int j0     = blockIdx.x * 16;
    const int g      = w * 512 + j0 + lane16;   // global gate row

    // ---- preload weight fragments (resident whole kernel) ----
    half8 bfi[16], bfh[16];
#pragma unroll
    for (int kt = 0; kt < 16; ++kt) {
        bfi[kt] = *(const half8*)&wi[(size_t)g * 512 + kt * 32 + k8];
        bfh[kt] = *(const half8*)&wh[(size_t)g * 512 + kt * 32 + k8];
    }
    const float bsum = bi[g] + bh[g];

    const int mE = w * 16 + lgrp * 4;
    float c[4];
#pragma unroll
    for (int r = 0; r < 4; ++r)
        c[r] = c0[(mE + r) * HDIM + j0 + lane16];

    __shared__ char  hlds[NBATCH * HDIM * 2];      // 64 KB staged h_{t-1}, XOR-swizzled
    __shared__ float glds[4 * 64 * 17];            // gates, pitch 17 (17 KB)
    __shared__ half_t hsl[NBATCH * 16];            // this block's h slice (2 KB)

    // ---- xacc = x_0 @ Wi^T (input projection for step 0) ----
    v4f xacc[4];
#pragma unroll
    for (int fm = 0; fm < 4; ++fm) xacc[fm] = (v4f)0.f;
    {
        const half_t* xt = xh;
#pragma unroll
        for (int kt = 0; kt < 16; ++kt)
#pragma unroll
            for (int fm = 0; fm < 4; ++fm) {
                half8 a = *(const half8*)&xt[(fm * 16 + lane16) * HDIM + kt * 32 + k8];
                xacc[fm] = __builtin_amdgcn_mfma_f32_16x16x32_f16(a, bfi[kt], xacc[fm], 0, 0, 0);
            }
    }

    for (int t = 0; t < SEQ; ++t) {
        const half_t* hin  = hbuf + (t & 1) * (NBATCH * HDIM);
        half_t*       hout = hbuf + ((t + 1) & 1) * (NBATCH * HDIM);

        // ---- wait for all blocks' h_{t-1} slices (device-coherent poll) ----
        if (t > 0) {
            if (w == 0) {
                const unsigned int* fp = flags + (size_t)(t - 1) * NBLK + (lane & 31);
                unsigned int f;
                do {
                    asm volatile("global_load_dword %0, %1, off sc0 sc1\n\t"
                                 "s_waitcnt vmcnt(0)"
                                 : "=v"(f) : "v"(fp) : "memory");
                } while (__ballot(f == 0u) != 0ull);
            }
            __syncthreads();
        }

        // ---- stage h_{t-1} (64 KB) into LDS with sc0/sc1 loads, swizzled ----
        {
            const u32x4* src = (const u32x4*)hin;
#pragma unroll
            for (int rnd = 0; rnd < 2; ++rnd) {
                u32x4 tmp[8];
#pragma unroll
                for (int i = 0; i < 8; ++i) {
                    const u32x4* p = src + (rnd * 8 + i) * 256 + tid;
                    asm volatile("global_load_dwordx4 %0, %1, off sc0 sc1"
                                 : "=v"(tmp[i]) : "v"(p) : "memory");
                }
                asm volatile("s_waitcnt vmcnt(0)" ::: "memory");
#pragma unroll
                for (int i = 0; i < 8; ++i) {
                    int n    = (rnd * 8 + i) * 256 + tid;   // 16B-granule index
                    int row  = n >> 6;                      // batch row (1 KB rows)
                    int slot = (n & 63) ^ (row & 7);        // XOR swizzle
                    *(u32x4*)(hlds + row * 1024 + slot * 16) = tmp[i];
                }
            }
        }
        __syncthreads();

        // ---- gates = xacc + h_{t-1} @ Wh^T ----
        v4f acc[4];
#pragma unroll
        for (int fm = 0; fm < 4; ++fm) acc[fm] = xacc[fm];
#pragma unroll
        for (int kt = 0; kt < 16; ++kt) {
            const int colb = kt * 64 + lgrp * 16;   // byte offset within row
#pragma unroll
            for (int fm = 0; fm < 4; ++fm) {
                const int row = fm * 16 + lane16;
                half8 a = *(const half8*)(hlds + row * 1024 + (colb ^ ((row & 7) << 4)));
                acc[fm] = __builtin_amdgcn_mfma_f32_16x16x32_f16(a, bfh[kt], acc[fm], 0, 0, 0);
            }
        }

        // ---- gates (+bias) to LDS; C-frag layout: col=lane16, row=fm*16+4*lgrp+r ----
#pragma unroll
        for (int fm = 0; fm < 4; ++fm)
#pragma unroll
            for (int r = 0; r < 4; ++r)
                glds[(w * 64 + fm * 16 + lgrp * 4 + r) * 17 + lane16] = acc[fm][r] + bsum;
        __syncthreads();

        // ---- elementwise: lane handles (m = mE+r, j = j0+lane16) ----
        const int jcol = j0 + lane16;
        float hv[4];
#pragma unroll
        for (int r = 0; r < 4; ++r) {
            const int m = mE + r;
            float F  = glds[(0 * 64 + m) * 17 + lane16];
            float I  = glds[(1 * 64 + m) * 17 + lane16];
            float G  = glds[(2 * 64 + m) * 17 + lane16];
            float O  = glds[(3 * 64 + m) * 17 + lane16];
            float f  = fsig(F);
            float i  = fsig(I);
            float gg = ftanh(G);
            float o  = fsig(O);
            float cn = f * c[r] + i * gg;
            c[r] = cn;
            hv[r] = o * ftanh(cn);
            hsl[m * 16 + lane16] = (half_t)hv[r];
        }
        __syncthreads();   // h slice complete in LDS

        // ---- publish h slice (sc0/sc1) then flag ----
        if (tid < 128) {
            const int m = tid >> 1;
            half_t* dst = hout + m * HDIM + j0 + (tid & 1) * 8;
            u32x4 val = *(const u32x4*)&hsl[m * 16 + (tid & 1) * 8];
            asm volatile("global_store_dwordx4 %0, %1, off sc0 sc1"
                         :: "v"(dst), "v"(val) : "memory");
        }
        __syncthreads();   // drains vmcnt for all waves -> slice at coherence point
        if (tid == 0) {
            unsigned int one = 1u;
            unsigned int* fp = flags + (size_t)t * NBLK + blockIdx.x;
            asm volatile("global_store_dword %0, %1, off sc0 sc1"
                         :: "v"(fp), "v"(one) : "memory");
        }

        // ---- off critical path: x-projection for step t+1 ----
        if (t + 1 < SEQ) {
            const half_t* xt1 = xh + (size_t)(t + 1) * (NBATCH * HDIM);
#pragma unroll
            for (int fm = 0; fm < 4; ++fm) xacc[fm] = (v4f)0.f;
#pragma unroll
            for (int kt = 0; kt < 16; ++kt)
#pragma unroll
                for (int fm = 0; fm < 4; ++fm) {
                    half8 a = *(const half8*)&xt1[(fm * 16 + lane16) * HDIM + kt * 32 + k8];
                    xacc[fm] = __builtin_amdgcn_mfma_f32_16x16x32_f16(a, bfi[kt], xacc[fm], 0, 0, 0);
                }
        }

        // ---- h_seq output stores (normal cached path) ----
#pragma unroll
        for (int r = 0; r < 4; ++r) {
            const int m = mE + r;
            out[((size_t)t * NBATCH + m) * HDIM + jcol] = hv[r];
            if (t == SEQ - 1) {
                out[HSEQ_ELEMS + (size_t)m * HDIM + jcol] = hv[r];
                out[HSEQ_ELEMS + (size_t)NBATCH * HDIM + (size_t)m * HDIM + jcol] = c[r];
            }
        }
    }
}

// ---------------- launch ----------------
extern "C" void kernel_launch(void* const* d_in, const int* in_sizes, int n_in,
                              void* d_out, int out_size, void* d_ws, size_t ws_size,
                              hipStream_t stream) {
    const float* x  = (const float*)d_in[0];
    const float* h0 = (const float*)d_in[1];
    const float* c0 = (const float*)d_in[2];
    const float* Wi = (const float*)d_in[3];
    const float* bi = (const float*)d_in[4];
    const float* Wh = (const float*)d_in[5];
    const float* bh = (const float*)d_in[6];
    float* out = (float*)d_out;

    char* ws = (char*)d_ws;
    // ws layout: flags @0 (128K) | hbuf @131072 (128K) | Wi_h @262144 (2M)
    //            | Wh_h @2359296 (2M) | x_h @4456448 (64M)  => ~68.3 MB
    unsigned int* flags = (unsigned int*)(ws + 0);
    half_t*       hbuf  = (half_t*)(ws + 131072);
    half_t*       wi_h  = (half_t*)(ws + 262144);
    half_t*       wh_h  = (half_t*)(ws + 2359296);
    half_t*       x_h   = (half_t*)(ws + 4456448);

    conv_f2h<<<4096, 256, 0, stream>>>((const float4*)x,  (half4_t*)x_h,  (SEQ * NBATCH * HDIM) / 4);
    conv_f2h<<<1024, 256, 0, stream>>>((const float4*)Wi, (half4_t*)wi_h, (4 * HDIM * HDIM) / 4);
    conv_f2h<<<1024, 256, 0, stream>>>((const float4*)Wh, (half4_t*)wh_h, (4 * HDIM * HDIM) / 4);
    prep_kernel<<<128, 256, 0, stream>>>(h0, hbuf, flags);
    lstm_rec<<<NBLK, 256, 0, stream>>>(x_h, wi_h, wh_h, bi, bh, c0, out, hbuf, flags);
}

// Round 3
// 16765.239 us; speedup vs baseline: 1.9221x; 1.0773x over previous
//
#include <hip/hip_runtime.h>

typedef _Float16 half_t;
typedef _Float16 half8 __attribute__((ext_vector_type(8)));
typedef _Float16 half4_t __attribute__((ext_vector_type(4)));
typedef float v4f __attribute__((ext_vector_type(4)));
typedef unsigned int u32x4 __attribute__((ext_vector_type(4)));

#define SEQ 1024
#define NBATCH 64
#define HDIM 512
#define NBLK 32
#define HSEQ_ELEMS ((size_t)SEQ * NBATCH * HDIM)

__device__ __forceinline__ float fsig(float x)  { return 1.f / (1.f + __expf(-x)); }
__device__ __forceinline__ float ftanh(float x) { return 1.f - 2.f / (__expf(2.f * x) + 1.f); }

// ---------------- fp32 -> fp16 conversion (vectorized) ----------------
__global__ void conv_f2h(const float4* __restrict__ src, half4_t* __restrict__ dst, int n4) {
    int idx = blockIdx.x * blockDim.x + threadIdx.x;
    int stride = gridDim.x * blockDim.x;
    for (int i = idx; i < n4; i += stride) {
        float4 v = src[i];
        half4_t h;
        h[0] = (half_t)v.x; h[1] = (half_t)v.y; h[2] = (half_t)v.z; h[3] = (half_t)v.w;
        dst[i] = h;
    }
}

// ---------------- init h buffer + per-step flags (every launch) ----------------
__global__ void prep_kernel(const float* __restrict__ h0, half_t* __restrict__ hbuf,
                            unsigned int* __restrict__ flags) {
    int idx = blockIdx.x * 256 + threadIdx.x;
    if (idx < NBATCH * HDIM) hbuf[idx] = (half_t)h0[idx];
    if (idx < SEQ * NBLK) flags[idx] = 0u;
}

// ---------------- persistent recurrent kernel ----------------
// 32 blocks x 256 threads, 1 block/CU. Block owns h-dims [j0,j0+16); wave w =
// gate type. Weights register-resident. Per-step pipeline:
//   poll(t-1) -> issue h-stage loads (sc0sc1) -> xproj(t+1) 1st half (hides
//   staging) -> LDS (rotate swizzle) -> h-MFMA -> gates -> elementwise ->
//   publish h slice + flag -> xproj(t+1) 2nd half (hides flag propagation).
__global__ __launch_bounds__(256, 1) void lstm_rec(
    const half_t* __restrict__ xh,   // (SEQ*64, 512) fp16
    const half_t* __restrict__ wi,   // (2048, 512) fp16
    const half_t* __restrict__ wh,   // (2048, 512) fp16
    const float*  __restrict__ bi,   // (2048)
    const float*  __restrict__ bh,   // (2048)
    const float*  __restrict__ c0,   // (64, 512)
    float*        __restrict__ out,  // h_seq | h | c
    half_t*       __restrict__ hbuf, // 2 * 64*512 fp16 ring
    unsigned int* __restrict__ flags)// SEQ * NBLK
{
    const int tid    = threadIdx.x;
    const int lane   = tid & 63;
    const int w      = tid >> 6;       // gate type 0..3
    const int lane16 = lane & 15;
    const int lgrp   = lane >> 4;      // 0..3
    const int k8     = lgrp * 8;
    const int j0     = blockIdx.x * 16;
    const int g      = w * 512 + j0 + lane16;   // global gate row

    // ---- preload weight fragments (resident whole kernel) ----
    half8 bfi[16], bfh[16];
#pragma unroll
    for (int kt = 0; kt < 16; ++kt) {
        bfi[kt] = *(const half8*)&wi[(size_t)g * 512 + kt * 32 + k8];
        bfh[kt] = *(const half8*)&wh[(size_t)g * 512 + kt * 32 + k8];
    }
    const float bsum = bi[g] + bh[g];

    const int mE = w * 16 + lgrp * 4;
    float c[4];
#pragma unroll
    for (int r = 0; r < 4; ++r)
        c[r] = c0[(mE + r) * HDIM + j0 + lane16];

    __shared__ char  hlds[NBATCH * HDIM * 2];      // 64 KB staged h_{t}, rotate-swizzled
    __shared__ float glds[4 * 64 * 17];            // gates, pitch 17
    __shared__ half_t hsl[NBATCH * 16];            // this block's h slice (2 KB)

    // ---- xa = x_0 @ Wi^T ----
    v4f xa[4];
#pragma unroll
    for (int fm = 0; fm < 4; ++fm) xa[fm] = (v4f)0.f;
    {
        const half_t* xt = xh;
#pragma unroll
        for (int kt = 0; kt < 16; ++kt)
#pragma unroll
            for (int fm = 0; fm < 4; ++fm) {
                half8 a = *(const half8*)&xt[(fm * 16 + lane16) * HDIM + kt * 32 + k8];
                xa[fm] = __builtin_amdgcn_mfma_f32_16x16x32_f16(a, bfi[kt], xa[fm], 0, 0, 0);
            }
    }

    for (int t = 0; t < SEQ; ++t) {
        const half_t* hin  = hbuf + (t & 1) * (NBATCH * HDIM);
        half_t*       hout = hbuf + ((t + 1) & 1) * (NBATCH * HDIM);
        const bool    more = (t + 1 < SEQ);

        // ---- wait for all blocks' h_t slices (device-coherent poll) ----
        if (t > 0) {
            if (w == 0) {
                const unsigned int* fp = flags + (size_t)(t - 1) * NBLK + (lane & 31);
                unsigned int f;
                do {
                    asm volatile("global_load_dword %0, %1, off sc0 sc1\n\t"
                                 "s_waitcnt vmcnt(0)"
                                 : "=v"(f) : "v"(fp) : "memory");
                } while (__ballot(f == 0u) != 0ull);
            }
            __syncthreads();
        }

        // ---- issue all 16 staging loads (sc0/sc1), no wait yet ----
        u32x4 tmp[16];
        {
            const u32x4* src = (const u32x4*)hin;
#pragma unroll
            for (int i = 0; i < 16; ++i) {
                const u32x4* p = src + i * 256 + tid;
                asm volatile("global_load_dwordx4 %0, %1, off sc0 sc1"
                             : "=v"(tmp[i]) : "v"(p) : "memory");
            }
        }

        // ---- x-projection for t+1, first half (hides staging latency) ----
        v4f xn[4];
#pragma unroll
        for (int fm = 0; fm < 4; ++fm) xn[fm] = (v4f)0.f;
        if (more) {
            const half_t* xt1 = xh + (size_t)(t + 1) * (NBATCH * HDIM);
#pragma unroll
            for (int kt = 0; kt < 8; ++kt)
#pragma unroll
                for (int fm = 0; fm < 4; ++fm) {
                    half8 a = *(const half8*)&xt1[(fm * 16 + lane16) * HDIM + kt * 32 + k8];
                    xn[fm] = __builtin_amdgcn_mfma_f32_16x16x32_f16(a, bfi[kt], xn[fm], 0, 0, 0);
                }
        }

        // ---- staged h -> LDS with rotate swizzle: row r, granule (g+r)&63 ----
        asm volatile("s_waitcnt vmcnt(0)" ::: "memory");
#pragma unroll
        for (int i = 0; i < 16; ++i) {
            int n    = i * 256 + tid;            // 16B-granule index 0..4095
            int row  = n >> 6;                   // batch row (1 KB rows)
            int gran = ((n & 63) + row) & 63;    // rotate swizzle
            *(u32x4*)(hlds + row * 1024 + gran * 16) = tmp[i];
        }
        __syncthreads();

        // ---- gates = xa + h_t @ Wh^T ----
        v4f acc[4];
#pragma unroll
        for (int fm = 0; fm < 4; ++fm) acc[fm] = xa[fm];
#pragma unroll
        for (int kt = 0; kt < 16; ++kt) {
#pragma unroll
            for (int fm = 0; fm < 4; ++fm) {
                const int row  = fm * 16 + lane16;
                const int gran = (kt * 4 + lgrp + row) & 63;
                half8 a = *(const half8*)(hlds + row * 1024 + gran * 16);
                acc[fm] = __builtin_amdgcn_mfma_f32_16x16x32_f16(a, bfh[kt], acc[fm], 0, 0, 0);
            }
        }

        // ---- gates (+bias) to LDS; C-frag: col=lane16, row=fm*16+4*lgrp+r ----
#pragma unroll
        for (int fm = 0; fm < 4; ++fm)
#pragma unroll
            for (int r = 0; r < 4; ++r)
                glds[(w * 64 + fm * 16 + lgrp * 4 + r) * 17 + lane16] = acc[fm][r] + bsum;
        __syncthreads();

        // ---- elementwise: lane handles (m = mE+r, j = j0+lane16) ----
        const int jcol = j0 + lane16;
        float hv[4];
#pragma unroll
        for (int r = 0; r < 4; ++r) {
            const int m = mE + r;
            float F  = glds[(0 * 64 + m) * 17 + lane16];
            float I  = glds[(1 * 64 + m) * 17 + lane16];
            float G  = glds[(2 * 64 + m) * 17 + lane16];
            float O  = glds[(3 * 64 + m) * 17 + lane16];
            float f  = fsig(F);
            float i  = fsig(I);
            float gg = ftanh(G);
            float o  = fsig(O);
            float cn = f * c[r] + i * gg;
            c[r] = cn;
            hv[r] = o * ftanh(cn);
            hsl[m * 16 + lane16] = (half_t)hv[r];
        }
        __syncthreads();   // h slice complete in LDS

        // ---- publish h slice (sc0/sc1) then flag ----
        if (tid < 128) {
            const int m = tid >> 1;
            half_t* dst = hout + m * HDIM + j0 + (tid & 1) * 8;
            u32x4 val = *(const u32x4*)&hsl[m * 16 + (tid & 1) * 8];
            asm volatile("global_store_dwordx4 %0, %1, off sc0 sc1"
                         :: "v"(dst), "v"(val) : "memory");
        }
        __syncthreads();   // drains vmcnt for all waves -> slice at coherence point
        if (tid == 0) {
            unsigned int one = 1u;
            unsigned int* fp = flags + (size_t)t * NBLK + blockIdx.x;
            asm volatile("global_store_dword %0, %1, off sc0 sc1"
                         :: "v"(fp), "v"(one) : "memory");
        }

        // ---- x-projection for t+1, second half (hides flag propagation) ----
        if (more) {
            const half_t* xt1 = xh + (size_t)(t + 1) * (NBATCH * HDIM);
#pragma unroll
            for (int kt = 8; kt < 16; ++kt)
#pragma unroll
                for (int fm = 0; fm < 4; ++fm) {
                    half8 a = *(const half8*)&xt1[(fm * 16 + lane16) * HDIM + kt * 32 + k8];
                    xn[fm] = __builtin_amdgcn_mfma_f32_16x16x32_f16(a, bfi[kt], xn[fm], 0, 0, 0);
                }
        }

        // ---- h_seq output stores (normal cached path) ----
#pragma unroll
        for (int r = 0; r < 4; ++r) {
            const int m = mE + r;
            out[((size_t)t * NBATCH + m) * HDIM + jcol] = hv[r];
            if (t == SEQ - 1) {
                out[HSEQ_ELEMS + (size_t)m * HDIM + jcol] = hv[r];
                out[HSEQ_ELEMS + (size_t)NBATCH * HDIM + (size_t)m * HDIM + jcol] = c[r];
            }
        }

        // ---- rotate x-projection buffers ----
#pragma unroll
        for (int fm = 0; fm < 4; ++fm) xa[fm] = xn[fm];
    }
}

// ---------------- launch ----------------
extern "C" void kernel_launch(void* const* d_in, const int* in_sizes, int n_in,
                              void* d_out, int out_size, void* d_ws, size_t ws_size,
                              hipStream_t stream) {
    const float* x  = (const float*)d_in[0];
    const float* h0 = (const float*)d_in[1];
    const float* c0 = (const float*)d_in[2];
    const float* Wi = (const float*)d_in[3];
    const float* bi = (const float*)d_in[4];
    const float* Wh = (const float*)d_in[5];
    const float* bh = (const float*)d_in[6];
    float* out = (float*)d_out;

    char* ws = (char*)d_ws;
    // ws layout: flags @0 (128K) | hbuf @131072 (128K) | Wi_h @262144 (2M)
    //            | Wh_h @2359296 (2M) | x_h @4456448 (64M)  => ~68.3 MB
    unsigned int* flags = (unsigned int*)(ws + 0);
    half_t*       hbuf  = (half_t*)(ws + 131072);
    half_t*       wi_h  = (half_t*)(ws + 262144);
    half_t*       wh_h  = (half_t*)(ws + 2359296);
    half_t*       x_h   = (half_t*)(ws + 4456448);

    conv_f2h<<<4096, 256, 0, stream>>>((const float4*)x,  (half4_t*)x_h,  (SEQ * NBATCH * HDIM) / 4);
    conv_f2h<<<1024, 256, 0, stream>>>((const float4*)Wi, (half4_t*)wi_h, (4 * HDIM * HDIM) / 4);
    conv_f2h<<<1024, 256, 0, stream>>>((const float4*)Wh, (half4_t*)wh_h, (4 * HDIM * HDIM) / 4);
    prep_kernel<<<128, 256, 0, stream>>>(h0, hbuf, flags);
    lstm_rec<<<NBLK, 256, 0, stream>>>(x_h, wi_h, wh_h, bi, bh, c0, out, hbuf, flags);
}

// Round 4
// 7757.352 us; speedup vs baseline: 4.1540x; 2.1612x over previous
//
#include <hip/hip_runtime.h>

typedef _Float16 half_t;
typedef _Float16 half8 __attribute__((ext_vector_type(8)));
typedef _Float16 half4_t __attribute__((ext_vector_type(4)));
typedef float v4f __attribute__((ext_vector_type(4)));
typedef unsigned int u32x4 __attribute__((ext_vector_type(4)));

#define SEQ 1024
#define NBATCH 64
#define HDIM 512
#define CREW 32
#define XTILE (NBATCH * HDIM)          // elems per step tile (32768)
#define HSEQ_ELEMS ((size_t)SEQ * NBATCH * HDIM)

__device__ __forceinline__ float fsig(float x)  { return 1.f / (1.f + __expf(-x)); }
__device__ __forceinline__ float ftanh(float x) { return 1.f - 2.f / (__expf(2.f * x) + 1.f); }

// ---------------- fp32 -> fp16 conversion (vectorized) ----------------
__global__ void conv_f2h(const float4* __restrict__ src, half4_t* __restrict__ dst, int n4) {
    int idx = blockIdx.x * blockDim.x + threadIdx.x;
    int stride = gridDim.x * blockDim.x;
    for (int i = idx; i < n4; i += stride) {
        float4 v = src[i];
        half4_t h;
        h[0] = (half_t)v.x; h[1] = (half_t)v.y; h[2] = (half_t)v.z; h[3] = (half_t)v.w;
        dst[i] = h;
    }
}

// ---------------- init h buffer + flags + tickets (every launch) ----------------
__global__ void prep_kernel(const float* __restrict__ h0, half_t* __restrict__ hbuf,
                            unsigned int* __restrict__ flags, unsigned int* __restrict__ xtick) {
    int idx = blockIdx.x * 256 + threadIdx.x;
    if (idx < 8) xtick[idx] = 0u;
    if (idx < SEQ * CREW) flags[idx] = 0u;          // 32768 words
    if (idx < XTILE) hbuf[idx] = (half_t)h0[idx];   // ring slot 0 = h0
}

// ---------------- persistent recurrent kernel, crew-of-32 on XCD 0 ----------------
// 1024 blocks launched; only the first 32 blocks resident on XCD0 become workers
// (ticket via atomicAdd). Workers are co-resident on 32 distinct CUs (147KB LDS
// => 1 block/CU), sharing XCD0's L2: all h/flag exchange uses sc0 (L1-bypass,
// L2-coherent) => ~0.1us instead of ~3us cross-XCD fabric ops.
// Block owns h-dims [rank*16, rank*16+16); wave w = gate type. Weights in VGPRs.
// x and h both staged through LDS (rotate swizzle) for MFMA fragment reads.
__global__ __launch_bounds__(256, 1) void lstm_rec(
    const half_t* __restrict__ xh,   // (SEQ*64, 512) fp16
    const half_t* __restrict__ wi,   // (2048, 512) fp16
    const half_t* __restrict__ wh,   // (2048, 512) fp16
    const float*  __restrict__ bi,   // (2048)
    const float*  __restrict__ bh,   // (2048)
    const float*  __restrict__ c0,   // (64, 512)
    float*        __restrict__ out,  // h_seq | h | c
    half_t*       __restrict__ hbuf, // 2 * 32768 fp16 ring
    unsigned int* __restrict__ flags,// SEQ * CREW
    unsigned int* __restrict__ xtick)// 8 ticket counters
{
    unsigned int xcd;
    asm volatile("s_getreg_b32 %0, hwreg(HW_REG_XCC_ID)" : "=s"(xcd));
    xcd &= 7u;
    if (xcd != 0u) return;

    __shared__ unsigned int rank_s;
    if (threadIdx.x == 0) rank_s = atomicAdd(&xtick[0], 1u);
    __syncthreads();
    const unsigned int rank = rank_s;
    if (rank >= CREW) return;

    const int tid    = threadIdx.x;
    const int lane   = tid & 63;
    const int w      = tid >> 6;       // gate type 0..3
    const int lane16 = lane & 15;
    const int lgrp   = lane >> 4;      // 0..3
    const int k8     = lgrp * 8;
    const int j0     = (int)rank * 16;
    const int g      = w * 512 + j0 + lane16;   // global gate row

    // ---- preload weight fragments (resident whole kernel) ----
    half8 bfi[16], bfh[16];
#pragma unroll
    for (int kt = 0; kt < 16; ++kt) {
        bfi[kt] = *(const half8*)&wi[(size_t)g * 512 + kt * 32 + k8];
        bfh[kt] = *(const half8*)&wh[(size_t)g * 512 + kt * 32 + k8];
    }
    const float bsum = bi[g] + bh[g];

    const int mE = w * 16 + lgrp * 4;
    float c[4];
#pragma unroll
    for (int r = 0; r < 4; ++r)
        c[r] = c0[(mE + r) * HDIM + j0 + lane16];

    __shared__ char   hlds[NBATCH * HDIM * 2];   // 64 KB h_{t-1}, rotate-swizzled
    __shared__ char   xlds[NBATCH * HDIM * 2];   // 64 KB x_{t+1}, rotate-swizzled
    __shared__ float  glds[4 * 64 * 17];         // gates, pitch 17
    __shared__ half_t hsl[NBATCH * 16];          // this block's h slice (2 KB)

    // ---- prologue: xa = x_0 @ Wi^T (direct from global; one-time) ----
    v4f xa[4];
#pragma unroll
    for (int fm = 0; fm < 4; ++fm) xa[fm] = (v4f)0.f;
#pragma unroll
    for (int kt = 0; kt < 16; ++kt)
#pragma unroll
        for (int fm = 0; fm < 4; ++fm) {
            half8 a = *(const half8*)&xh[(fm * 16 + lane16) * HDIM + kt * 32 + k8];
            xa[fm] = __builtin_amdgcn_mfma_f32_16x16x32_f16(a, bfi[kt], xa[fm], 0, 0, 0);
        }
    __syncthreads();

    for (int t = 0; t < SEQ; ++t) {
        const half_t* hin  = hbuf + (t & 1) * XTILE;
        half_t*       hout = hbuf + ((t + 1) & 1) * XTILE;

        // ---- wait for all blocks' h_{t-1} slices (intra-XCD L2 poll, sc0) ----
        if (t > 0) {
            if (w == 0) {
                const unsigned int* fp = flags + (size_t)(t - 1) * CREW + (lane & 31);
                unsigned int f;
                do {
                    asm volatile("global_load_dword %0, %1, off sc0\n\t"
                                 "s_waitcnt vmcnt(0)"
                                 : "=v"(f) : "v"(fp) : "memory");
                } while (__ballot(f == 0u) != 0ull);
            }
            __syncthreads();   // B1
        }

        // ---- issue h staging loads (sc0, L2) then x_{t+1} loads (plain) ----
        u32x4 th[16], tx[16];
        {
            const u32x4* hsrc = (const u32x4*)hin;
#pragma unroll
            for (int i = 0; i < 16; ++i)
                asm volatile("global_load_dwordx4 %0, %1, off sc0"
                             : "=v"(th[i]) : "v"(hsrc + i * 256 + tid) : "memory");
            const int tn = (t + 1 < SEQ) ? (t + 1) : t;
            const u32x4* xsrc = (const u32x4*)(xh + (size_t)tn * XTILE);
#pragma unroll
            for (int i = 0; i < 16; ++i)
                asm volatile("global_load_dwordx4 %0, %1, off"
                             : "=v"(tx[i]) : "v"(xsrc + i * 256 + tid) : "memory");
        }

        // ---- h arrives first (issued first): wait to 16 outstanding ----
        asm volatile("s_waitcnt vmcnt(16)" ::: "memory");
#pragma unroll
        for (int i = 0; i < 16; ++i) {
            int n    = i * 256 + tid;
            int row  = n >> 6;
            int gran = ((n & 63) + row) & 63;    // rotate swizzle
            *(u32x4*)(hlds + row * 1024 + gran * 16) = th[i];
        }
        asm volatile("s_waitcnt vmcnt(0)" ::: "memory");
#pragma unroll
        for (int i = 0; i < 16; ++i) {
            int n    = i * 256 + tid;
            int row  = n >> 6;
            int gran = ((n & 63) + row) & 63;
            *(u32x4*)(xlds + row * 1024 + gran * 16) = tx[i];
        }
        __syncthreads();   // B2

        // ---- gates = xa + h_{t-1} @ Wh^T ----
        v4f acc[4];
#pragma unroll
        for (int fm = 0; fm < 4; ++fm) acc[fm] = xa[fm];
#pragma unroll
        for (int kt = 0; kt < 16; ++kt) {
#pragma unroll
            for (int fm = 0; fm < 4; ++fm) {
                const int row  = fm * 16 + lane16;
                const int gran = (kt * 4 + lgrp + row) & 63;
                half8 a = *(const half8*)(hlds + row * 1024 + gran * 16);
                acc[fm] = __builtin_amdgcn_mfma_f32_16x16x32_f16(a, bfh[kt], acc[fm], 0, 0, 0);
            }
        }

        // ---- gates (+bias) to LDS; C-frag: col=lane16, row=fm*16+4*lgrp+r ----
#pragma unroll
        for (int fm = 0; fm < 4; ++fm)
#pragma unroll
            for (int r = 0; r < 4; ++r)
                glds[(w * 64 + fm * 16 + lgrp * 4 + r) * 17 + lane16] = acc[fm][r] + bsum;
        __syncthreads();   // B3

        // ---- elementwise: lane handles (m = mE+r, j = j0+lane16) ----
        const int jcol = j0 + lane16;
        float hv[4];
#pragma unroll
        for (int r = 0; r < 4; ++r) {
            const int m = mE + r;
            float F  = glds[(0 * 64 + m) * 17 + lane16];
            float I  = glds[(1 * 64 + m) * 17 + lane16];
            float G  = glds[(2 * 64 + m) * 17 + lane16];
            float O  = glds[(3 * 64 + m) * 17 + lane16];
            float f  = fsig(F);
            float i  = fsig(I);
            float gg = ftanh(G);
            float o  = fsig(O);
            float cn = f * c[r] + i * gg;
            c[r] = cn;
            hv[r] = o * ftanh(cn);
            hsl[m * 16 + lane16] = (half_t)hv[r];
        }
        __syncthreads();   // B4

        // ---- publish h slice into L2 (sc0) then flag ----
        if (tid < 128) {
            const int m = tid >> 1;
            half_t* dst = hout + m * HDIM + j0 + (tid & 1) * 8;
            u32x4 val = *(const u32x4*)&hsl[m * 16 + (tid & 1) * 8];
            asm volatile("global_store_dwordx4 %0, %1, off sc0"
                         :: "v"(dst), "v"(val) : "memory");
        }
        asm volatile("s_waitcnt vmcnt(0)" ::: "memory");
        __syncthreads();   // B5: all publish stores in L2
        if (tid == 0) {
            unsigned int one = 1u;
            unsigned int* fp = flags + (size_t)t * CREW + rank;
            asm volatile("global_store_dword %0, %1, off sc0"
                         :: "v"(fp), "v"(one) : "memory");
        }

        // ---- off critical path: h_seq stores (plain cached) ----
#pragma unroll
        for (int r = 0; r < 4; ++r) {
            const int m = mE + r;
            out[((size_t)t * NBATCH + m) * HDIM + jcol] = hv[r];
            if (t == SEQ - 1) {
                out[HSEQ_ELEMS + (size_t)m * HDIM + jcol] = hv[r];
                out[HSEQ_ELEMS + (size_t)NBATCH * HDIM + (size_t)m * HDIM + jcol] = c[r];
            }
        }

        // ---- off critical path: xproj for t+1 from xlds ----
        v4f xn[4];
#pragma unroll
        for (int fm = 0; fm < 4; ++fm) xn[fm] = (v4f)0.f;
#pragma unroll
        for (int kt = 0; kt < 16; ++kt) {
#pragma unroll
            for (int fm = 0; fm < 4; ++fm) {
                const int row  = fm * 16 + lane16;
                const int gran = (kt * 4 + lgrp + row) & 63;
                half8 a = *(const half8*)(xlds + row * 1024 + gran * 16);
                xn[fm] = __builtin_amdgcn_mfma_f32_16x16x32_f16(a, bfi[kt], xn[fm], 0, 0, 0);
            }
        }
#pragma unroll
        for (int fm = 0; fm < 4; ++fm) xa[fm] = xn[fm];
    }
}

// ---------------- launch ----------------
extern "C" void kernel_launch(void* const* d_in, const int* in_sizes, int n_in,
                              void* d_out, int out_size, void* d_ws, size_t ws_size,
                              hipStream_t stream) {
    const float* x  = (const float*)d_in[0];
    const float* h0 = (const float*)d_in[1];
    const float* c0 = (const float*)d_in[2];
    const float* Wi = (const float*)d_in[3];
    const float* bi = (const float*)d_in[4];
    const float* Wh = (const float*)d_in[5];
    const float* bh = (const float*)d_in[6];
    float* out = (float*)d_out;

    char* ws = (char*)d_ws;
    // ws layout: xtick @0 (4K) | flags @4096 (128K) | hbuf @135168 (128K)
    //            | Wi_h @266240 (2M) | Wh_h @2363392 (2M) | x_h @4460544 (64M) => ~71.5 MB
    unsigned int* xtick = (unsigned int*)(ws + 0);
    unsigned int* flags = (unsigned int*)(ws + 4096);
    half_t*       hbuf  = (half_t*)(ws + 135168);
    half_t*       wi_h  = (half_t*)(ws + 266240);
    half_t*       wh_h  = (half_t*)(ws + 2363392);
    half_t*       x_h   = (half_t*)(ws + 4460544);

    conv_f2h<<<4096, 256, 0, stream>>>((const float4*)x,  (half4_t*)x_h,  (SEQ * NBATCH * HDIM) / 4);
    conv_f2h<<<1024, 256, 0, stream>>>((const float4*)Wi, (half4_t*)wi_h, (4 * HDIM * HDIM) / 4);
    conv_f2h<<<1024, 256, 0, stream>>>((const float4*)Wh, (half4_t*)wh_h, (4 * HDIM * HDIM) / 4);
    prep_kernel<<<128, 256, 0, stream>>>(h0, hbuf, flags, xtick);
    lstm_rec<<<1024, 256, 0, stream>>>(x_h, wi_h, wh_h, bi, bh, c0, out, hbuf, flags, xtick);
}

// Round 7
// 7502.084 us; speedup vs baseline: 4.2954x; 1.0340x over previous
//
#include <hip/hip_runtime.h>

typedef _Float16 half_t;
typedef _Float16 half8 __attribute__((ext_vector_type(8)));
typedef _Float16 half4v __attribute__((ext_vector_type(4)));
typedef _Float16 half4_t __attribute__((ext_vector_type(4)));
typedef float v4f __attribute__((ext_vector_type(4)));
typedef unsigned int u32x4 __attribute__((ext_vector_type(4)));
typedef unsigned int u32x2 __attribute__((ext_vector_type(2)));

#define SEQ 1024
#define NBATCH 64
#define HDIM 512
#define CREW 32
#define XTILE (NBATCH * HDIM)          // 32768 halves per step tile
#define HSEQ_ELEMS ((size_t)SEQ * NBATCH * HDIM)

__device__ __forceinline__ float fsig(float x)  { return 1.f / (1.f + __expf(-x)); }
__device__ __forceinline__ float ftanh(float x) { return 1.f - 2.f / (__expf(2.f * x) + 1.f); }

// ---------------- fp32 -> fp16 conversion ----------------
__global__ void conv_f2h(const float4* __restrict__ src, half4_t* __restrict__ dst, int n4) {
    int idx = blockIdx.x * blockDim.x + threadIdx.x;
    int stride = gridDim.x * blockDim.x;
    for (int i = idx; i < n4; i += stride) {
        float4 v = src[i];
        half4_t h;
        h[0] = (half_t)v.x; h[1] = (half_t)v.y; h[2] = (half_t)v.z; h[3] = (half_t)v.w;
        dst[i] = h;
    }
}

// ---------------- init h ring slot0 + flags + tickets (every launch) ----------------
__global__ void prep_kernel(const float* __restrict__ h0, half_t* __restrict__ hbuf,
                            unsigned int* __restrict__ flags, unsigned int* __restrict__ xtick) {
    int idx = blockIdx.x * 256 + threadIdx.x;
    if (idx < 8) xtick[idx] = 0u;
    if (idx < SEQ * CREW) flags[idx] = 0u;
    if (idx < XTILE) hbuf[idx] = (half_t)h0[idx];
}

// ---------------- persistent recurrent kernel: single crew of 32 on XCD0 ----------------
// Proven round-4 skeleton: 1024 blocks launched, XCD0 blocks take tickets, first
// 32 become workers (1 block/CU via 146KB LDS). Block rank owns j-dims
// [rank*16,rank*16+16); wave w = gate type; weights register-resident; all h/flag
// exchange intra-XCD via sc0 (L2-coherent).
// r7 changes vs r4 (intra-block only): x-staging moved off the serial chain
// (only h waits before B2; xlds fill + xproj at loop tail), elementwise remapped
// to (1 batch x 4 contiguous j) per lane so h publishes straight from registers
// (drops the hsl LDS hop + one barrier), "=&v" on all asm load outputs.
__global__ __launch_bounds__(256, 1) void lstm_rec(
    const half_t* __restrict__ xh,   // (SEQ*64, 512) fp16
    const half_t* __restrict__ wi,   // (2048, 512) fp16
    const half_t* __restrict__ wh,   // (2048, 512) fp16
    const float*  __restrict__ bi,   // (2048)
    const float*  __restrict__ bh,   // (2048)
    const float*  __restrict__ c0,   // (64, 512)
    float*        __restrict__ out,  // h_seq | h | c
    half_t*       __restrict__ hbuf, // 2 * XTILE fp16 ring
    unsigned int* __restrict__ flags,// SEQ * CREW
    unsigned int* __restrict__ xtick)// 8 ticket counters
{
    unsigned int xcd;
    asm volatile("s_getreg_b32 %0, hwreg(HW_REG_XCC_ID)" : "=s"(xcd));
    if ((xcd & 7u) != 0u) return;

    __shared__ unsigned int rank_s;
    if (threadIdx.x == 0) rank_s = atomicAdd(&xtick[0], 1u);
    __syncthreads();
    const unsigned int rank = rank_s;
    if (rank >= CREW) return;

    __shared__ char  hlds[XTILE * 2];      // 64 KB h_{t-1}, rotate-swizzled
    __shared__ char  xlds[XTILE * 2];      // 64 KB x_{t+1}, rotate-swizzled
    __shared__ float glds[4 * 64 * 17];    // gates [gate][batch] pitch 17

    const int tid    = threadIdx.x;
    const int lane   = tid & 63;
    const int w      = tid >> 6;        // gate type 0..3
    const int lane16 = lane & 15;
    const int lgrp   = lane >> 4;       // 0..3
    const int k8     = lgrp * 8;
    const int j0     = (int)rank * 16;
    const int g      = w * 512 + j0 + lane16;   // global gate row

    // ---- weights resident in VGPRs ----
    half8 bfi[16], bfh[16];
#pragma unroll
    for (int kt = 0; kt < 16; ++kt) {
        bfi[kt] = *(const half8*)&wi[(size_t)g * 512 + kt * 32 + k8];
        bfh[kt] = *(const half8*)&wh[(size_t)g * 512 + kt * 32 + k8];
    }
    const float bsum = bi[g] + bh[g];

    // ---- elementwise/publish mapping: lane owns (batch mrow, j = j0+jsub..+3) ----
    const int mrow = w * 16 + (lane >> 2);
    const int jsub = (lane & 3) * 4;
    float c[4];
    {
        float4 cv = *(const float4*)&c0[(size_t)mrow * HDIM + j0 + jsub];
        c[0] = cv.x; c[1] = cv.y; c[2] = cv.z; c[3] = cv.w;
    }

    // ---- prologue: xa = x_0 @ Wi^T (direct global reads) ----
    v4f xa[4];
#pragma unroll
    for (int fm = 0; fm < 4; ++fm) xa[fm] = (v4f)0.f;
#pragma unroll
    for (int kt = 0; kt < 16; ++kt)
#pragma unroll
        for (int fm = 0; fm < 4; ++fm) {
            half8 a = *(const half8*)&xh[(size_t)(fm * 16 + lane16) * HDIM + kt * 32 + k8];
            xa[fm] = __builtin_amdgcn_mfma_f32_16x16x32_f16(a, bfi[kt], xa[fm], 0, 0, 0);
        }

    for (int t = 0; t < SEQ; ++t) {
        const half_t* hin  = hbuf + (t & 1) * XTILE;
        half_t*       hout = hbuf + ((t + 1) & 1) * XTILE;

        // ---- wave 0 polls crew flags for h_{t-1} (bounded fail-fast) ----
        if (t > 0) {
            if (w == 0) {
                const unsigned int* fp = flags + (size_t)(t - 1) * CREW + (lane & 31);
                unsigned int f;
                int guard = 0;
                do {
                    asm volatile("global_load_dword %0, %1, off sc0\n\t"
                                 "s_waitcnt vmcnt(0)"
                                 : "=&v"(f) : "v"(fp) : "memory");
                } while (__ballot(f == 0u) != 0ull && ++guard < (1 << 18));
            }
            __syncthreads();   // B1
        }

        // ---- issue 16 h loads (sc0) then 16 x loads (plain); wait only for h ----
        u32x4 th[16], tx[16];
        {
            const u32x4* hsrc = (const u32x4*)hin;
#pragma unroll
            for (int i = 0; i < 16; ++i)
                asm volatile("global_load_dwordx4 %0, %1, off sc0"
                             : "=&v"(th[i]) : "v"(hsrc + i * 256 + tid) : "memory");
            const int tn = (t + 1 < SEQ) ? (t + 1) : t;
            const u32x4* xsrc = (const u32x4*)(xh + (size_t)tn * XTILE);
#pragma unroll
            for (int i = 0; i < 16; ++i)
                asm volatile("global_load_dwordx4 %0, %1, off"
                             : "=&v"(tx[i]) : "v"(xsrc + i * 256 + tid) : "memory");
        }
        asm volatile("s_waitcnt vmcnt(16)" ::: "memory");   // th done, tx in flight
#pragma unroll
        for (int i = 0; i < 16; ++i) {
            int n   = i * 256 + tid;          // 16B-granule index
            int row = n >> 6;                 // batch row (1 KB rows)
            int gr  = ((n & 63) + row) & 63;  // rotate swizzle
            *(u32x4*)(hlds + row * 1024 + gr * 16) = th[i];
        }
        __syncthreads();   // B2

        // ---- gates = xa + h_{t-1} @ Wh^T ----
        v4f acc[4];
#pragma unroll
        for (int fm = 0; fm < 4; ++fm) acc[fm] = xa[fm];
#pragma unroll
        for (int kt = 0; kt < 16; ++kt) {
#pragma unroll
            for (int fm = 0; fm < 4; ++fm) {
                const int row = fm * 16 + lane16;
                const int gr  = (kt * 4 + lgrp + row) & 63;
                half8 a = *(const half8*)(hlds + row * 1024 + gr * 16);
                acc[fm] = __builtin_amdgcn_mfma_f32_16x16x32_f16(a, bfh[kt], acc[fm], 0, 0, 0);
            }
        }

        // ---- gates (+bias) to LDS; C-frag: col(j)=lane16, row(m)=fm*16+4*lgrp+r ----
#pragma unroll
        for (int fm = 0; fm < 4; ++fm)
#pragma unroll
            for (int r = 0; r < 4; ++r)
                glds[(w * 64 + fm * 16 + lgrp * 4 + r) * 17 + lane16] = acc[fm][r] + bsum;
        __syncthreads();   // B3

        // ---- elementwise: lane owns batch mrow, j = j0+jsub..jsub+3 ----
        float hv[4];
#pragma unroll
        for (int r = 0; r < 4; ++r) {
            float F  = glds[(0 * 64 + mrow) * 17 + jsub + r];
            float I  = glds[(1 * 64 + mrow) * 17 + jsub + r];
            float G  = glds[(2 * 64 + mrow) * 17 + jsub + r];
            float O  = glds[(3 * 64 + mrow) * 17 + jsub + r];
            float f  = fsig(F);
            float i_ = fsig(I);
            float gg = ftanh(G);
            float o  = fsig(O);
            float cn = f * c[r] + i_ * gg;
            c[r] = cn;
            hv[r] = o * ftanh(cn);
        }

        // ---- publish h (register -> sc0 dwordx2), drain, barrier, flag ----
        {
            half4v hp;
#pragma unroll
            for (int r = 0; r < 4; ++r) hp[r] = (half_t)hv[r];
            half_t* dst = hout + (size_t)mrow * HDIM + j0 + jsub;
            asm volatile("global_store_dwordx2 %0, %1, off sc0"
                         :: "v"(dst), "v"(*(u32x2*)&hp) : "memory");
        }
        asm volatile("s_waitcnt vmcnt(0)" ::: "memory");   // publish (and tx) complete
        __syncthreads();   // B4: every thread's publish is in L2
        if (tid == 0) {
            unsigned int one = 1u;
            unsigned int* fp = flags + (size_t)t * CREW + rank;
            asm volatile("global_store_dword %0, %1, off sc0"
                         :: "v"(fp), "v"(one) : "memory");
        }

        // ---- off inter-block path: h_seq / final outputs ----
        {
            float4 o4; o4.x = hv[0]; o4.y = hv[1]; o4.z = hv[2]; o4.w = hv[3];
            *(float4*)&out[((size_t)t * NBATCH + mrow) * HDIM + j0 + jsub] = o4;
            if (t == SEQ - 1) {
                *(float4*)&out[HSEQ_ELEMS + (size_t)mrow * HDIM + j0 + jsub] = o4;
                float4 c4; c4.x = c[0]; c4.y = c[1]; c4.z = c[2]; c4.w = c[3];
                *(float4*)&out[HSEQ_ELEMS + (size_t)NBATCH * HDIM
                               + (size_t)mrow * HDIM + j0 + jsub] = c4;
            }
        }

        // ---- x_{t+1} -> LDS (tx already drained), then xproj for t+1 ----
#pragma unroll
        for (int i = 0; i < 16; ++i) {
            int n   = i * 256 + tid;
            int row = n >> 6;
            int gr  = ((n & 63) + row) & 63;
            *(u32x4*)(xlds + row * 1024 + gr * 16) = tx[i];
        }
        __syncthreads();   // B5

        if (t + 1 < SEQ) {
            v4f xn[4];
#pragma unroll
            for (int fm = 0; fm < 4; ++fm) xn[fm] = (v4f)0.f;
#pragma unroll
            for (int kt = 0; kt < 16; ++kt) {
#pragma unroll
                for (int fm = 0; fm < 4; ++fm) {
                    const int row = fm * 16 + lane16;
                    const int gr  = (kt * 4 + lgrp + row) & 63;
                    half8 a = *(const half8*)(xlds + row * 1024 + gr * 16);
                    xn[fm] = __builtin_amdgcn_mfma_f32_16x16x32_f16(a, bfi[kt], xn[fm], 0, 0, 0);
                }
            }
#pragma unroll
            for (int fm = 0; fm < 4; ++fm) xa[fm] = xn[fm];
        }
    }
}

// ---------------- launch ----------------
extern "C" void kernel_launch(void* const* d_in, const int* in_sizes, int n_in,
                              void* d_out, int out_size, void* d_ws, size_t ws_size,
                              hipStream_t stream) {
    const float* x  = (const float*)d_in[0];
    const float* h0 = (const float*)d_in[1];
    const float* c0 = (const float*)d_in[2];
    const float* Wi = (const float*)d_in[3];
    const float* bi = (const float*)d_in[4];
    const float* Wh = (const float*)d_in[5];
    const float* bh = (const float*)d_in[6];
    float* out = (float*)d_out;

    char* ws = (char*)d_ws;
    // ws layout (bytes): xtick @0 (4K) | flags @4096 (128K) | hbuf @135168 (128K)
    //   | Wi_h @266240 (2M) | Wh_h @2363392 (2M) | x_h @4460544 (64M) => ~68.5 MB
    unsigned int* xtick = (unsigned int*)(ws + 0);
    unsigned int* flags = (unsigned int*)(ws + 4096);
    half_t*       hbuf  = (half_t*)(ws + 135168);
    half_t*       wi_h  = (half_t*)(ws + 266240);
    half_t*       wh_h  = (half_t*)(ws + 2363392);
    half_t*       x_h   = (half_t*)(ws + 4460544);

    conv_f2h<<<4096, 256, 0, stream>>>((const float4*)x,  (half4_t*)x_h,  (SEQ * NBATCH * HDIM) / 4);
    conv_f2h<<<1024, 256, 0, stream>>>((const float4*)Wi, (half4_t*)wi_h, (4 * HDIM * HDIM) / 4);
    conv_f2h<<<1024, 256, 0, stream>>>((const float4*)Wh, (half4_t*)wh_h, (4 * HDIM * HDIM) / 4);
    prep_kernel<<<128, 256, 0, stream>>>(h0, hbuf, flags, xtick);
    lstm_rec<<<1024, 256, 0, stream>>>(x_h, wi_h, wh_h, bi, bh, c0, out, hbuf, flags, xtick);
}

// Round 8
// 7476.025 us; speedup vs baseline: 4.3103x; 1.0035x over previous
//
#include <hip/hip_runtime.h>

typedef _Float16 half_t;
typedef _Float16 half8 __attribute__((ext_vector_type(8)));
typedef _Float16 half4v __attribute__((ext_vector_type(4)));
typedef _Float16 half4_t __attribute__((ext_vector_type(4)));
typedef float v4f __attribute__((ext_vector_type(4)));
typedef unsigned int u32x4 __attribute__((ext_vector_type(4)));
typedef unsigned int u32x2 __attribute__((ext_vector_type(2)));

#define SEQ 1024
#define NBATCH 64
#define HDIM 512
#define CREW 32
#define XTILE (NBATCH * HDIM)          // 32768 halves per step tile
#define HSEQ_ELEMS ((size_t)SEQ * NBATCH * HDIM)

__device__ __forceinline__ float fsig(float x)  { return 1.f / (1.f + __expf(-x)); }
__device__ __forceinline__ float ftanh(float x) { return 1.f - 2.f / (__expf(2.f * x) + 1.f); }

// ---------------- fp32 -> fp16 conversion ----------------
__global__ void conv_f2h(const float4* __restrict__ src, half4_t* __restrict__ dst, int n4) {
    int idx = blockIdx.x * blockDim.x + threadIdx.x;
    int stride = gridDim.x * blockDim.x;
    for (int i = idx; i < n4; i += stride) {
        float4 v = src[i];
        half4_t h;
        h[0] = (half_t)v.x; h[1] = (half_t)v.y; h[2] = (half_t)v.z; h[3] = (half_t)v.w;
        dst[i] = h;
    }
}

// ---------------- init h ring slot0 + flags + tickets (every launch) ----------------
__global__ void prep_kernel(const float* __restrict__ h0, half_t* __restrict__ hbuf,
                            unsigned int* __restrict__ flags, unsigned int* __restrict__ xtick) {
    int idx = blockIdx.x * 256 + threadIdx.x;
    if (idx < 8) xtick[idx] = 0u;
    if (idx < SEQ * CREW) flags[idx] = 0u;
    if (idx < XTILE) hbuf[idx] = (half_t)h0[idx];
}

// ---------------- persistent recurrent kernel: single crew of 32 on XCD0 ----------------
// Proven round-4 skeleton: 1024 blocks launched, XCD0 blocks take tickets, first
// 32 become workers (1 block/CU via 146KB LDS). Block rank owns j-dims
// [rank*16,rank*16+16); wave w = gate type; weights register-resident; all h/flag
// exchange intra-XCD via sc0 (L2-coherent).
// r7 changes vs r4 (intra-block only): x-staging moved off the serial chain
// (only h waits before B2; xlds fill + xproj at loop tail), elementwise remapped
// to (1 batch x 4 contiguous j) per lane so h publishes straight from registers
// (drops the hsl LDS hop + one barrier), "=&v" on all asm load outputs.
__global__ __launch_bounds__(256, 1) void lstm_rec(
    const half_t* __restrict__ xh,   // (SEQ*64, 512) fp16
    const half_t* __restrict__ wi,   // (2048, 512) fp16
    const half_t* __restrict__ wh,   // (2048, 512) fp16
    const float*  __restrict__ bi,   // (2048)
    const float*  __restrict__ bh,   // (2048)
    const float*  __restrict__ c0,   // (64, 512)
    float*        __restrict__ out,  // h_seq | h | c
    half_t*       __restrict__ hbuf, // 2 * XTILE fp16 ring
    unsigned int* __restrict__ flags,// SEQ * CREW
    unsigned int* __restrict__ xtick)// 8 ticket counters
{
    unsigned int xcd;
    asm volatile("s_getreg_b32 %0, hwreg(HW_REG_XCC_ID)" : "=s"(xcd));
    if ((xcd & 7u) != 0u) return;

    __shared__ unsigned int rank_s;
    if (threadIdx.x == 0) rank_s = atomicAdd(&xtick[0], 1u);
    __syncthreads();
    const unsigned int rank = rank_s;
    if (rank >= CREW) return;

    __shared__ char  hlds[XTILE * 2];      // 64 KB h_{t-1}, rotate-swizzled
    __shared__ char  xlds[XTILE * 2];      // 64 KB x_{t+1}, rotate-swizzled
    __shared__ float glds[4 * 64 * 17];    // gates [gate][batch] pitch 17

    const int tid    = threadIdx.x;
    const int lane   = tid & 63;
    const int w      = tid >> 6;        // gate type 0..3
    const int lane16 = lane & 15;
    const int lgrp   = lane >> 4;       // 0..3
    const int k8     = lgrp * 8;
    const int j0     = (int)rank * 16;
    const int g      = w * 512 + j0 + lane16;   // global gate row

    // ---- weights resident in VGPRs ----
    half8 bfi[16], bfh[16];
#pragma unroll
    for (int kt = 0; kt < 16; ++kt) {
        bfi[kt] = *(const half8*)&wi[(size_t)g * 512 + kt * 32 + k8];
        bfh[kt] = *(const half8*)&wh[(size_t)g * 512 + kt * 32 + k8];
    }
    const float bsum = bi[g] + bh[g];

    // ---- elementwise/publish mapping: lane owns (batch mrow, j = j0+jsub..+3) ----
    const int mrow = w * 16 + (lane >> 2);
    const int jsub = (lane & 3) * 4;
    float c[4];
    {
        float4 cv = *(const float4*)&c0[(size_t)mrow * HDIM + j0 + jsub];
        c[0] = cv.x; c[1] = cv.y; c[2] = cv.z; c[3] = cv.w;
    }

    // ---- prologue: xa = x_0 @ Wi^T (direct global reads) ----
    v4f xa[4];
#pragma unroll
    for (int fm = 0; fm < 4; ++fm) xa[fm] = (v4f)0.f;
#pragma unroll
    for (int kt = 0; kt < 16; ++kt)
#pragma unroll
        for (int fm = 0; fm < 4; ++fm) {
            half8 a = *(const half8*)&xh[(size_t)(fm * 16 + lane16) * HDIM + kt * 32 + k8];
            xa[fm] = __builtin_amdgcn_mfma_f32_16x16x32_f16(a, bfi[kt], xa[fm], 0, 0, 0);
        }

    for (int t = 0; t < SEQ; ++t) {
        const half_t* hin  = hbuf + (t & 1) * XTILE;
        half_t*       hout = hbuf + ((t + 1) & 1) * XTILE;

        // ---- wave 0 polls crew flags for h_{t-1} (bounded fail-fast) ----
        if (t > 0) {
            if (w == 0) {
                const unsigned int* fp = flags + (size_t)(t - 1) * CREW + (lane & 31);
                unsigned int f;
                int guard = 0;
                do {
                    asm volatile("global_load_dword %0, %1, off sc0\n\t"
                                 "s_waitcnt vmcnt(0)"
                                 : "=&v"(f) : "v"(fp) : "memory");
                } while (__ballot(f == 0u) != 0ull && ++guard < (1 << 18));
            }
            __syncthreads();   // B1
        }

        // ---- issue 16 h loads (sc0) then 16 x loads (plain); wait only for h ----
        u32x4 th[16], tx[16];
        {
            const u32x4* hsrc = (const u32x4*)hin;
#pragma unroll
            for (int i = 0; i < 16; ++i)
                asm volatile("global_load_dwordx4 %0, %1, off sc0"
                             : "=&v"(th[i]) : "v"(hsrc + i * 256 + tid) : "memory");
            const int tn = (t + 1 < SEQ) ? (t + 1) : t;
            const u32x4* xsrc = (const u32x4*)(xh + (size_t)tn * XTILE);
#pragma unroll
            for (int i = 0; i < 16; ++i)
                asm volatile("global_load_dwordx4 %0, %1, off"
                             : "=&v"(tx[i]) : "v"(xsrc + i * 256 + tid) : "memory");
        }
        asm volatile("s_waitcnt vmcnt(16)" ::: "memory");   // th done, tx in flight
#pragma unroll
        for (int i = 0; i < 16; ++i) {
            int n   = i * 256 + tid;          // 16B-granule index
            int row = n >> 6;                 // batch row (1 KB rows)
            int gr  = ((n & 63) + row) & 63;  // rotate swizzle
            *(u32x4*)(hlds + row * 1024 + gr * 16) = th[i];
        }
        __syncthreads();   // B2

        // ---- gates = xa + h_{t-1} @ Wh^T ----
        v4f acc[4];
#pragma unroll
        for (int fm = 0; fm < 4; ++fm) acc[fm] = xa[fm];
#pragma unroll
        for (int kt = 0; kt < 16; ++kt) {
#pragma unroll
            for (int fm = 0; fm < 4; ++fm) {
                const int row = fm * 16 + lane16;
                const int gr  = (kt * 4 + lgrp + row) & 63;
                half8 a = *(const half8*)(hlds + row * 1024 + gr * 16);
                acc[fm] = __builtin_amdgcn_mfma_f32_16x16x32_f16(a, bfh[kt], acc[fm], 0, 0, 0);
            }
        }

        // ---- gates (+bias) to LDS; C-frag: col(j)=lane16, row(m)=fm*16+4*lgrp+r ----
#pragma unroll
        for (int fm = 0; fm < 4; ++fm)
#pragma unroll
            for (int r = 0; r < 4; ++r)
                glds[(w * 64 + fm * 16 + lgrp * 4 + r) * 17 + lane16] = acc[fm][r] + bsum;
        __syncthreads();   // B3

        // ---- elementwise: lane owns batch mrow, j = j0+jsub..jsub+3 ----
        float hv[4];
#pragma unroll
        for (int r = 0; r < 4; ++r) {
            float F  = glds[(0 * 64 + mrow) * 17 + jsub + r];
            float I  = glds[(1 * 64 + mrow) * 17 + jsub + r];
            float G  = glds[(2 * 64 + mrow) * 17 + jsub + r];
            float O  = glds[(3 * 64 + mrow) * 17 + jsub + r];
            float f  = fsig(F);
            float i_ = fsig(I);
            float gg = ftanh(G);
            float o  = fsig(O);
            float cn = f * c[r] + i_ * gg;
            c[r] = cn;
            hv[r] = o * ftanh(cn);
        }

        // ---- publish h (register -> sc0 dwordx2), drain, barrier, flag ----
        {
            half4v hp;
#pragma unroll
            for (int r = 0; r < 4; ++r) hp[r] = (half_t)hv[r];
            half_t* dst = hout + (size_t)mrow * HDIM + j0 + jsub;
            asm volatile("global_store_dwordx2 %0, %1, off sc0"
                         :: "v"(dst), "v"(*(u32x2*)&hp) : "memory");
        }
        asm volatile("s_waitcnt vmcnt(0)" ::: "memory");   // publish (and tx) complete
        __syncthreads();   // B4: every thread's publish is in L2
        if (tid == 0) {
            unsigned int one = 1u;
            unsigned int* fp = flags + (size_t)t * CREW + rank;
            asm volatile("global_store_dword %0, %1, off sc0"
                         :: "v"(fp), "v"(one) : "memory");
        }

        // ---- off inter-block path: h_seq / final outputs ----
        {
            float4 o4; o4.x = hv[0]; o4.y = hv[1]; o4.z = hv[2]; o4.w = hv[3];
            *(float4*)&out[((size_t)t * NBATCH + mrow) * HDIM + j0 + jsub] = o4;
            if (t == SEQ - 1) {
                *(float4*)&out[HSEQ_ELEMS + (size_t)mrow * HDIM + j0 + jsub] = o4;
                float4 c4; c4.x = c[0]; c4.y = c[1]; c4.z = c[2]; c4.w = c[3];
                *(float4*)&out[HSEQ_ELEMS + (size_t)NBATCH * HDIM
                               + (size_t)mrow * HDIM + j0 + jsub] = c4;
            }
        }

        // ---- x_{t+1} -> LDS (tx already drained), then xproj for t+1 ----
#pragma unroll
        for (int i = 0; i < 16; ++i) {
            int n   = i * 256 + tid;
            int row = n >> 6;
            int gr  = ((n & 63) + row) & 63;
            *(u32x4*)(xlds + row * 1024 + gr * 16) = tx[i];
        }
        __syncthreads();   // B5

        if (t + 1 < SEQ) {
            v4f xn[4];
#pragma unroll
            for (int fm = 0; fm < 4; ++fm) xn[fm] = (v4f)0.f;
#pragma unroll
            for (int kt = 0; kt < 16; ++kt) {
#pragma unroll
                for (int fm = 0; fm < 4; ++fm) {
                    const int row = fm * 16 + lane16;
                    const int gr  = (kt * 4 + lgrp + row) & 63;
                    half8 a = *(const half8*)(xlds + row * 1024 + gr * 16);
                    xn[fm] = __builtin_amdgcn_mfma_f32_16x16x32_f16(a, bfi[kt], xn[fm], 0, 0, 0);
                }
            }
#pragma unroll
            for (int fm = 0; fm < 4; ++fm) xa[fm] = xn[fm];
        }
    }
}

// ---------------- launch ----------------
extern "C" void kernel_launch(void* const* d_in, const int* in_sizes, int n_in,
                              void* d_out, int out_size, void* d_ws, size_t ws_size,
                              hipStream_t stream) {
    const float* x  = (const float*)d_in[0];
    const float* h0 = (const float*)d_in[1];
    const float* c0 = (const float*)d_in[2];
    const float* Wi = (const float*)d_in[3];
    const float* bi = (const float*)d_in[4];
    const float* Wh = (const float*)d_in[5];
    const float* bh = (const float*)d_in[6];
    float* out = (float*)d_out;

    char* ws = (char*)d_ws;
    // ws layout (bytes): xtick @0 (4K) | flags @4096 (128K) | hbuf @135168 (128K)
    //   | Wi_h @266240 (2M) | Wh_h @2363392 (2M) | x_h @4460544 (64M) => ~68.5 MB
    unsigned int* xtick = (unsigned int*)(ws + 0);
    unsigned int* flags = (unsigned int*)(ws + 4096);
    half_t*       hbuf  = (half_t*)(ws + 135168);
    half_t*       wi_h  = (half_t*)(ws + 266240);
    half_t*       wh_h  = (half_t*)(ws + 2363392);
    half_t*       x_h   = (half_t*)(ws + 4460544);

    conv_f2h<<<4096, 256, 0, stream>>>((const float4*)x,  (half4_t*)x_h,  (SEQ * NBATCH * HDIM) / 4);
    conv_f2h<<<1024, 256, 0, stream>>>((const float4*)Wi, (half4_t*)wi_h, (4 * HDIM * HDIM) / 4);
    conv_f2h<<<1024, 256, 0, stream>>>((const float4*)Wh, (half4_t*)wh_h, (4 * HDIM * HDIM) / 4);
    prep_kernel<<<128, 256, 0, stream>>>(h0, hbuf, flags, xtick);
    lstm_rec<<<1024, 256, 0, stream>>>(x_h, wi_h, wh_h, bi, bh, c0, out, hbuf, flags, xtick);
}

// Round 9
// 7472.578 us; speedup vs baseline: 4.3123x; 1.0005x over previous
//
#include <hip/hip_runtime.h>

typedef _Float16 half_t;
typedef _Float16 half8 __attribute__((ext_vector_type(8)));
typedef _Float16 half4v __attribute__((ext_vector_type(4)));
typedef _Float16 half4_t __attribute__((ext_vector_type(4)));
typedef float v4f __attribute__((ext_vector_type(4)));
typedef unsigned int u32x4 __attribute__((ext_vector_type(4)));
typedef unsigned int u32x2 __attribute__((ext_vector_type(2)));

#define SEQ 1024
#define NBATCH 64
#define HDIM 512
#define CREW 32
#define XTILE (NBATCH * HDIM)          // 32768 halves per step tile
#define HSEQ_ELEMS ((size_t)SEQ * NBATCH * HDIM)

__device__ __forceinline__ float fsig(float x)  { return 1.f / (1.f + __expf(-x)); }
__device__ __forceinline__ float ftanh(float x) { return 1.f - 2.f / (__expf(2.f * x) + 1.f); }

// ---------------- fp32 -> fp16 conversion ----------------
__global__ void conv_f2h(const float4* __restrict__ src, half4_t* __restrict__ dst, int n4) {
    int idx = blockIdx.x * blockDim.x + threadIdx.x;
    int stride = gridDim.x * blockDim.x;
    for (int i = idx; i < n4; i += stride) {
        float4 v = src[i];
        half4_t h;
        h[0] = (half_t)v.x; h[1] = (half_t)v.y; h[2] = (half_t)v.z; h[3] = (half_t)v.w;
        dst[i] = h;
    }
}

// ---------------- init h ring slot0 + flags + tickets (every launch) ----------------
__global__ void prep_kernel(const float* __restrict__ h0, half_t* __restrict__ hbuf,
                            unsigned int* __restrict__ flags, unsigned int* __restrict__ xtick) {
    int idx = blockIdx.x * 256 + threadIdx.x;
    if (idx < 8) xtick[idx] = 0u;
    if (idx < SEQ * CREW) flags[idx] = 0u;
    if (idx < XTILE) hbuf[idx] = (half_t)h0[idx];
}

// ---------------- persistent recurrent kernel: single crew of 32 on XCD0 ----------------
// Proven round-4 skeleton: 1024 blocks launched, XCD0 blocks take tickets, first
// 32 become workers (1 block/CU via 146KB LDS). Block rank owns j-dims
// [rank*16,rank*16+16); wave w = gate type; weights register-resident; all h/flag
// exchange intra-XCD via sc0 (L2-coherent).
// r7 changes vs r4 (intra-block only): x-staging moved off the serial chain
// (only h waits before B2; xlds fill + xproj at loop tail), elementwise remapped
// to (1 batch x 4 contiguous j) per lane so h publishes straight from registers
// (drops the hsl LDS hop + one barrier), "=&v" on all asm load outputs.
__global__ __launch_bounds__(256, 1) void lstm_rec(
    const half_t* __restrict__ xh,   // (SEQ*64, 512) fp16
    const half_t* __restrict__ wi,   // (2048, 512) fp16
    const half_t* __restrict__ wh,   // (2048, 512) fp16
    const float*  __restrict__ bi,   // (2048)
    const float*  __restrict__ bh,   // (2048)
    const float*  __restrict__ c0,   // (64, 512)
    float*        __restrict__ out,  // h_seq | h | c
    half_t*       __restrict__ hbuf, // 2 * XTILE fp16 ring
    unsigned int* __restrict__ flags,// SEQ * CREW
    unsigned int* __restrict__ xtick)// 8 ticket counters
{
    unsigned int xcd;
    asm volatile("s_getreg_b32 %0, hwreg(HW_REG_XCC_ID)" : "=s"(xcd));
    if ((xcd & 7u) != 0u) return;

    __shared__ unsigned int rank_s;
    if (threadIdx.x == 0) rank_s = atomicAdd(&xtick[0], 1u);
    __syncthreads();
    const unsigned int rank = rank_s;
    if (rank >= CREW) return;

    __shared__ char  hlds[XTILE * 2];      // 64 KB h_{t-1}, rotate-swizzled
    __shared__ char  xlds[XTILE * 2];      // 64 KB x_{t+1}, rotate-swizzled
    __shared__ float glds[4 * 64 * 17];    // gates [gate][batch] pitch 17

    const int tid    = threadIdx.x;
    const int lane   = tid & 63;
    const int w      = tid >> 6;        // gate type 0..3
    const int lane16 = lane & 15;
    const int lgrp   = lane >> 4;       // 0..3
    const int k8     = lgrp * 8;
    const int j0     = (int)rank * 16;
    const int g      = w * 512 + j0 + lane16;   // global gate row

    // ---- weights resident in VGPRs ----
    half8 bfi[16], bfh[16];
#pragma unroll
    for (int kt = 0; kt < 16; ++kt) {
        bfi[kt] = *(const half8*)&wi[(size_t)g * 512 + kt * 32 + k8];
        bfh[kt] = *(const half8*)&wh[(size_t)g * 512 + kt * 32 + k8];
    }
    const float bsum = bi[g] + bh[g];

    // ---- elementwise/publish mapping: lane owns (batch mrow, j = j0+jsub..+3) ----
    const int mrow = w * 16 + (lane >> 2);
    const int jsub = (lane & 3) * 4;
    float c[4];
    {
        float4 cv = *(const float4*)&c0[(size_t)mrow * HDIM + j0 + jsub];
        c[0] = cv.x; c[1] = cv.y; c[2] = cv.z; c[3] = cv.w;
    }

    // ---- prologue: xa = x_0 @ Wi^T (direct global reads) ----
    v4f xa[4];
#pragma unroll
    for (int fm = 0; fm < 4; ++fm) xa[fm] = (v4f)0.f;
#pragma unroll
    for (int kt = 0; kt < 16; ++kt)
#pragma unroll
        for (int fm = 0; fm < 4; ++fm) {
            half8 a = *(const half8*)&xh[(size_t)(fm * 16 + lane16) * HDIM + kt * 32 + k8];
            xa[fm] = __builtin_amdgcn_mfma_f32_16x16x32_f16(a, bfi[kt], xa[fm], 0, 0, 0);
        }

    for (int t = 0; t < SEQ; ++t) {
        const half_t* hin  = hbuf + (t & 1) * XTILE;
        half_t*       hout = hbuf + ((t + 1) & 1) * XTILE;

        // ---- wave 0 polls crew flags for h_{t-1} (bounded fail-fast) ----
        if (t > 0) {
            if (w == 0) {
                const unsigned int* fp = flags + (size_t)(t - 1) * CREW + (lane & 31);
                unsigned int f;
                int guard = 0;
                do {
                    asm volatile("global_load_dword %0, %1, off sc0\n\t"
                                 "s_waitcnt vmcnt(0)"
                                 : "=&v"(f) : "v"(fp) : "memory");
                } while (__ballot(f == 0u) != 0ull && ++guard < (1 << 18));
            }
            __syncthreads();   // B1
        }

        // ---- issue 16 h loads (sc0) then 16 x loads (plain); wait only for h ----
        u32x4 th[16], tx[16];
        {
            const u32x4* hsrc = (const u32x4*)hin;
#pragma unroll
            for (int i = 0; i < 16; ++i)
                asm volatile("global_load_dwordx4 %0, %1, off sc0"
                             : "=&v"(th[i]) : "v"(hsrc + i * 256 + tid) : "memory");
            const int tn = (t + 1 < SEQ) ? (t + 1) : t;
            const u32x4* xsrc = (const u32x4*)(xh + (size_t)tn * XTILE);
#pragma unroll
            for (int i = 0; i < 16; ++i)
                asm volatile("global_load_dwordx4 %0, %1, off"
                             : "=&v"(tx[i]) : "v"(xsrc + i * 256 + tid) : "memory");
        }
        asm volatile("s_waitcnt vmcnt(16)" ::: "memory");   // th done, tx in flight
#pragma unroll
        for (int i = 0; i < 16; ++i) {
            int n   = i * 256 + tid;          // 16B-granule index
            int row = n >> 6;                 // batch row (1 KB rows)
            int gr  = ((n & 63) + row) & 63;  // rotate swizzle
            *(u32x4*)(hlds + row * 1024 + gr * 16) = th[i];
        }
        __syncthreads();   // B2

        // ---- gates = xa + h_{t-1} @ Wh^T ----
        v4f acc[4];
#pragma unroll
        for (int fm = 0; fm < 4; ++fm) acc[fm] = xa[fm];
#pragma unroll
        for (int kt = 0; kt < 16; ++kt) {
#pragma unroll
            for (int fm = 0; fm < 4; ++fm) {
                const int row = fm * 16 + lane16;
                const int gr  = (kt * 4 + lgrp + row) & 63;
                half8 a = *(const half8*)(hlds + row * 1024 + gr * 16);
                acc[fm] = __builtin_amdgcn_mfma_f32_16x16x32_f16(a, bfh[kt], acc[fm], 0, 0, 0);
            }
        }

        // ---- gates (+bias) to LDS; C-frag: col(j)=lane16, row(m)=fm*16+4*lgrp+r ----
#pragma unroll
        for (int fm = 0; fm < 4; ++fm)
#pragma unroll
            for (int r = 0; r < 4; ++r)
                glds[(w * 64 + fm * 16 + lgrp * 4 + r) * 17 + lane16] = acc[fm][r] + bsum;
        __syncthreads();   // B3

        // ---- elementwise: lane owns batch mrow, j = j0+jsub..jsub+3 ----
        float hv[4];
#pragma unroll
        for (int r = 0; r < 4; ++r) {
            float F  = glds[(0 * 64 + mrow) * 17 + jsub + r];
            float I  = glds[(1 * 64 + mrow) * 17 + jsub + r];
            float G  = glds[(2 * 64 + mrow) * 17 + jsub + r];
            float O  = glds[(3 * 64 + mrow) * 17 + jsub + r];
            float f  = fsig(F);
            float i_ = fsig(I);
            float gg = ftanh(G);
            float o  = fsig(O);
            float cn = f * c[r] + i_ * gg;
            c[r] = cn;
            hv[r] = o * ftanh(cn);
        }

        // ---- publish h (register -> sc0 dwordx2), drain, barrier, flag ----
        {
            half4v hp;
#pragma unroll
            for (int r = 0; r < 4; ++r) hp[r] = (half_t)hv[r];
            half_t* dst = hout + (size_t)mrow * HDIM + j0 + jsub;
            asm volatile("global_store_dwordx2 %0, %1, off sc0"
                         :: "v"(dst), "v"(*(u32x2*)&hp) : "memory");
        }
        asm volatile("s_waitcnt vmcnt(0)" ::: "memory");   // publish (and tx) complete
        __syncthreads();   // B4: every thread's publish is in L2
        if (tid == 0) {
            unsigned int one = 1u;
            unsigned int* fp = flags + (size_t)t * CREW + rank;
            asm volatile("global_store_dword %0, %1, off sc0"
                         :: "v"(fp), "v"(one) : "memory");
        }

        // ---- off inter-block path: h_seq / final outputs ----
        {
            float4 o4; o4.x = hv[0]; o4.y = hv[1]; o4.z = hv[2]; o4.w = hv[3];
            *(float4*)&out[((size_t)t * NBATCH + mrow) * HDIM + j0 + jsub] = o4;
            if (t == SEQ - 1) {
                *(float4*)&out[HSEQ_ELEMS + (size_t)mrow * HDIM + j0 + jsub] = o4;
                float4 c4; c4.x = c[0]; c4.y = c[1]; c4.z = c[2]; c4.w = c[3];
                *(float4*)&out[HSEQ_ELEMS + (size_t)NBATCH * HDIM
                               + (size_t)mrow * HDIM + j0 + jsub] = c4;
            }
        }

        // ---- x_{t+1} -> LDS (tx already drained), then xproj for t+1 ----
#pragma unroll
        for (int i = 0; i < 16; ++i) {
            int n   = i * 256 + tid;
            int row = n >> 6;
            int gr  = ((n & 63) + row) & 63;
            *(u32x4*)(xlds + row * 1024 + gr * 16) = tx[i];
        }
        __syncthreads();   // B5

        if (t + 1 < SEQ) {
            v4f xn[4];
#pragma unroll
            for (int fm = 0; fm < 4; ++fm) xn[fm] = (v4f)0.f;
#pragma unroll
            for (int kt = 0; kt < 16; ++kt) {
#pragma unroll
                for (int fm = 0; fm < 4; ++fm) {
                    const int row = fm * 16 + lane16;
                    const int gr  = (kt * 4 + lgrp + row) & 63;
                    half8 a = *(const half8*)(xlds + row * 1024 + gr * 16);
                    xn[fm] = __builtin_amdgcn_mfma_f32_16x16x32_f16(a, bfi[kt], xn[fm], 0, 0, 0);
                }
            }
#pragma unroll
            for (int fm = 0; fm < 4; ++fm) xa[fm] = xn[fm];
        }
    }
}

// ---------------- launch ----------------
extern "C" void kernel_launch(void* const* d_in, const int* in_sizes, int n_in,
                              void* d_out, int out_size, void* d_ws, size_t ws_size,
                              hipStream_t stream) {
    const float* x  = (const float*)d_in[0];
    const float* h0 = (const float*)d_in[1];
    const float* c0 = (const float*)d_in[2];
    const float* Wi = (const float*)d_in[3];
    const float* bi = (const float*)d_in[4];
    const float* Wh = (const float*)d_in[5];
    const float* bh = (const float*)d_in[6];
    float* out = (float*)d_out;

    char* ws = (char*)d_ws;
    // ws layout (bytes): xtick @0 (4K) | flags @4096 (128K) | hbuf @135168 (128K)
    //   | Wi_h @266240 (2M) | Wh_h @2363392 (2M) | x_h @4460544 (64M) => ~68.5 MB
    unsigned int* xtick = (unsigned int*)(ws + 0);
    unsigned int* flags = (unsigned int*)(ws + 4096);
    half_t*       hbuf  = (half_t*)(ws + 135168);
    half_t*       wi_h  = (half_t*)(ws + 266240);
    half_t*       wh_h  = (half_t*)(ws + 2363392);
    half_t*       x_h   = (half_t*)(ws + 4460544);

    conv_f2h<<<4096, 256, 0, stream>>>((const float4*)x,  (half4_t*)x_h,  (SEQ * NBATCH * HDIM) / 4);
    conv_f2h<<<1024, 256, 0, stream>>>((const float4*)Wi, (half4_t*)wi_h, (4 * HDIM * HDIM) / 4);
    conv_f2h<<<1024, 256, 0, stream>>>((const float4*)Wh, (half4_t*)wh_h, (4 * HDIM * HDIM) / 4);
    prep_kernel<<<128, 256, 0, stream>>>(h0, hbuf, flags, xtick);
    lstm_rec<<<1024, 256, 0, stream>>>(x_h, wi_h, wh_h, bi, bh, c0, out, hbuf, flags, xtick);
}